// Round 1
// baseline (841.121 us; speedup 1.0000x reference)
//
#include <hip/hip_runtime.h>

#define NEG 0.2f
#define EPSV 1e-16f

__device__ __forceinline__ unsigned enc_f(float x) {
  unsigned u = __float_as_uint(x);
  return (u & 0x80000000u) ? ~u : (u | 0x80000000u);
}
__device__ __forceinline__ float dec_f(unsigned u) {
  unsigned b = (u & 0x80000000u) ? (u ^ 0x80000000u) : ~u;
  return __uint_as_float(b);
}
__device__ __forceinline__ float lrelu(float x) { return x > 0.f ? x : NEG * x; }

// Hout[N,M] = X[N,K] @ W[K,M].  W staged in LDS, R rows per block, 256 threads.
template <int K, int M, int R>
__global__ __launch_bounds__(256) void k_gemm(const float* __restrict__ X,
                                              const float* __restrict__ W,
                                              float* __restrict__ Hout, int N) {
  __shared__ float ws[K * M];
  __shared__ float xs[R * K];
  const int tid = threadIdx.x;
  for (int idx = tid * 4; idx < K * M; idx += 1024)
    *(float4*)&ws[idx] = *(const float4*)&W[idx];
  const long row0 = (long)blockIdx.x * R;
  const int nrow = (int)min((long)R, (long)N - row0);
  for (int idx = tid * 4; idx < R * K; idx += 1024) {
    int r = idx / K;
    float4 v = make_float4(0.f, 0.f, 0.f, 0.f);
    if (r < nrow) v = *(const float4*)&X[row0 * K + idx];
    *(float4*)&xs[idx] = v;
  }
  __syncthreads();
  constexpr int NCT = M / 4;       // col tiles of 4
  constexpr int RS = 256 / NCT;    // row slots
  const int c0 = (tid % NCT) * 4;
  const int rslot = tid / NCT;
  for (int r = rslot; r < R; r += RS) {
    float4 acc = make_float4(0.f, 0.f, 0.f, 0.f);
#pragma unroll
    for (int k = 0; k < K; k += 4) {
      float4 xv = *(float4*)&xs[r * K + k];
      float4 w0 = *(float4*)&ws[(k + 0) * M + c0];
      float4 w1 = *(float4*)&ws[(k + 1) * M + c0];
      float4 w2 = *(float4*)&ws[(k + 2) * M + c0];
      float4 w3 = *(float4*)&ws[(k + 3) * M + c0];
      acc.x += xv.x * w0.x + xv.y * w1.x + xv.z * w2.x + xv.w * w3.x;
      acc.y += xv.x * w0.y + xv.y * w1.y + xv.z * w2.y + xv.w * w3.y;
      acc.z += xv.x * w0.z + xv.y * w1.z + xv.z * w2.z + xv.w * w3.z;
      acc.w += xv.x * w0.w + xv.y * w1.w + xv.z * w2.w + xv.w * w3.w;
    }
    if (r < nrow) *(float4*)&Hout[(row0 + r) * M + c0] = acc;
  }
}

// a_src[n,h] = <H[n,h,:], att_src[h,:]> ; same for a_dst
template <int H, int C>
__global__ void k_att(const float* __restrict__ Hf, const float* __restrict__ atts,
                      const float* __restrict__ attd, float* __restrict__ as_,
                      float* __restrict__ ad_, int N) {
  int t = blockIdx.x * 256 + threadIdx.x;
  if (t >= N * H) return;
  int n = t / H, h = t % H;
  const float* hp = Hf + (long)n * (H * C) + h * C;
  const float* sp = atts + h * C;
  const float* dp = attd + h * C;
  float s = 0.f, d = 0.f;
#pragma unroll
  for (int c = 0; c < C; c += 4) {
    float4 hv = *(const float4*)&hp[c];
    float4 sv = *(const float4*)&sp[c];
    float4 dv = *(const float4*)&dp[c];
    s += hv.x * sv.x + hv.y * sv.y + hv.z * sv.z + hv.w * sv.w;
    d += hv.x * dv.x + hv.y * dv.y + hv.z * dv.z + hv.w * dv.w;
  }
  as_[t] = s;
  ad_[t] = d;
}

// m[n,h] = enc(leaky(a_src[n,h] + a_dst[n,h]))   (self-loop initializes max)
__global__ void k_init_m(const float* __restrict__ as_, const float* __restrict__ ad_,
                         unsigned* __restrict__ m, int NH) {
  int t = blockIdx.x * 256 + threadIdx.x;
  if (t < NH) m[t] = enc_f(lrelu(as_[t] + ad_[t]));
}

template <int H>
__global__ void k_edge_max(const int* __restrict__ src, const int* __restrict__ dst,
                           const float* __restrict__ as_, const float* __restrict__ ad_,
                           unsigned* __restrict__ m, int E) {
  int t = blockIdx.x * 256 + threadIdx.x;
  if (t >= E * H) return;
  int e = t / H, h = t % H;
  int j = src[e], i = dst[e];
  float a = lrelu(as_[j * H + h] + ad_[i * H + h]);
  atomicMax(&m[i * H + h], enc_f(a));
}

// denom init with the self-loop term
__global__ void k_self_denom(const float* __restrict__ as_, const float* __restrict__ ad_,
                             const unsigned* __restrict__ m, float* __restrict__ dn, int NH) {
  int t = blockIdx.x * 256 + threadIdx.x;
  if (t >= NH) return;
  float a = lrelu(as_[t] + ad_[t]);
  dn[t] = expf(a - dec_f(m[t]));
}

template <int H>
__global__ void k_edge_denom(const int* __restrict__ src, const int* __restrict__ dst,
                             const float* __restrict__ as_, const float* __restrict__ ad_,
                             const unsigned* __restrict__ m, float* __restrict__ dn, int E) {
  int t = blockIdx.x * 256 + threadIdx.x;
  if (t >= E * H) return;
  int e = t / H, h = t % H;
  int j = src[e], i = dst[e];
  float a = lrelu(as_[j * H + h] + ad_[i * H + h]);
  atomicAdd(&dn[i * H + h], expf(a - dec_f(m[i * H + h])));
}

// acc[n,:] = p_self * H[n,:]  (full overwrite -> also serves as init)
template <int H, int C>
__global__ void k_self_agg(const float* __restrict__ Hf, const float* __restrict__ as_,
                           const float* __restrict__ ad_, const unsigned* __restrict__ m,
                           const float* __restrict__ dn, float* __restrict__ acc, long NF) {
  long t = (long)blockIdx.x * 256 + threadIdx.x;
  if (t >= NF) return;
  constexpr int F = H * C;
  int n = (int)(t / F), f = (int)(t % F);
  int h = f / C;
  float a = lrelu(as_[n * H + h] + ad_[n * H + h]);
  float p = expf(a - dec_f(m[n * H + h])) / (dn[n * H + h] + EPSV);
  acc[t] = p * Hf[t];
}

template <int H, int C>
__global__ void k_edge_agg(const int* __restrict__ src, const int* __restrict__ dst,
                           const float* __restrict__ Hf, const float* __restrict__ as_,
                           const float* __restrict__ ad_, const unsigned* __restrict__ m,
                           const float* __restrict__ dn, float* __restrict__ acc, long EF) {
  long t = (long)blockIdx.x * 256 + threadIdx.x;
  if (t >= EF) return;
  constexpr int F = H * C;
  int e = (int)(t / F), f = (int)(t % F);
  int h = f / C;
  int j = src[e], i = dst[e];
  float a = lrelu(as_[j * H + h] + ad_[i * H + h]);
  float p = expf(a - dec_f(m[i * H + h])) / (dn[i * H + h] + EPSV);
  atomicAdd(&acc[(long)i * F + f], p * Hf[(long)j * F + f]);
}

template <int F, bool RELU>
__global__ void k_bias(float* __restrict__ acc, const float* __restrict__ b, long NF) {
  long t = (long)blockIdx.x * 256 + threadIdx.x;
  if (t >= NF) return;
  int f = (int)(t % F);
  float v = acc[t] + b[f];
  acc[t] = RELU ? fmaxf(v, 0.f) : v;
}

extern "C" void kernel_launch(void* const* d_in, const int* in_sizes, int n_in,
                              void* d_out, int out_size, void* d_ws, size_t ws_size,
                              hipStream_t stream) {
  const float* x = (const float*)d_in[0];
  const int* ei = (const int*)d_in[1];
  const float* W1 = (const float*)d_in[2];
  const float* s1 = (const float*)d_in[3];
  const float* dd1 = (const float*)d_in[4];
  const float* b1 = (const float*)d_in[5];
  const float* W2 = (const float*)d_in[6];
  const float* s2 = (const float*)d_in[7];
  const float* dd2 = (const float*)d_in[8];
  const float* b2 = (const float*)d_in[9];
  const int N = in_sizes[0] / 128;
  const int E = in_sizes[1] / 2;
  const int* src = ei;      // row 0: source j
  const int* dst = ei + E;  // row 1: target i

  // workspace layout (with reuse between layers): N*288 floats = 57.6 MB
  float* wsp = (float*)d_ws;
  float* H1 = wsp;                         // N*128  (layer2: H2 lives here)
  float* as1 = H1 + (size_t)N * 128;       // N*8    (layer2: as2)
  float* ad1 = as1 + (size_t)N * 8;        // N*8    (layer2: ad2)
  unsigned* m1 = (unsigned*)(ad1 + (size_t)N * 8);  // N*8 (layer2: m2)
  float* dn1 = (float*)(m1 + (size_t)N * 8);        // N*8 (layer2: dn2)
  float* X2 = dn1 + (size_t)N * 8;         // N*128
  float* out = (float*)d_out;

  float* H2 = H1;
  float* as2 = as1;
  float* ad2 = ad1;
  unsigned* m2 = m1;
  float* dn2 = dn1;

  dim3 B(256);
  auto nb = [](long n) { return dim3((unsigned)((n + 255) / 256)); };

  // ---------- Layer 1: heads=8, C=16 ----------
  k_gemm<128, 128, 16><<<dim3((N + 15) / 16), B, 0, stream>>>(x, W1, H1, N);
  k_att<8, 16><<<nb((long)N * 8), B, 0, stream>>>(H1, s1, dd1, as1, ad1, N);
  k_init_m<<<nb((long)N * 8), B, 0, stream>>>(as1, ad1, m1, N * 8);
  k_edge_max<8><<<nb((long)E * 8), B, 0, stream>>>(src, dst, as1, ad1, m1, E);
  k_self_denom<<<nb((long)N * 8), B, 0, stream>>>(as1, ad1, m1, dn1, N * 8);
  k_edge_denom<8><<<nb((long)E * 8), B, 0, stream>>>(src, dst, as1, ad1, m1, dn1, E);
  k_self_agg<8, 16><<<nb((long)N * 128), B, 0, stream>>>(H1, as1, ad1, m1, dn1, X2, (long)N * 128);
  k_edge_agg<8, 16><<<nb((long)E * 128), B, 0, stream>>>(src, dst, H1, as1, ad1, m1, dn1, X2, (long)E * 128);
  k_bias<128, true><<<nb((long)N * 128), B, 0, stream>>>(X2, b1, (long)N * 128);

  // ---------- Layer 2: heads=1, C=64 ----------
  k_gemm<128, 64, 16><<<dim3((N + 15) / 16), B, 0, stream>>>(X2, W2, H2, N);
  k_att<1, 64><<<nb((long)N), B, 0, stream>>>(H2, s2, dd2, as2, ad2, N);
  k_init_m<<<nb((long)N), B, 0, stream>>>(as2, ad2, m2, N);
  k_edge_max<1><<<nb((long)E), B, 0, stream>>>(src, dst, as2, ad2, m2, E);
  k_self_denom<<<nb((long)N), B, 0, stream>>>(as2, ad2, m2, dn2, N);
  k_edge_denom<1><<<nb((long)E), B, 0, stream>>>(src, dst, as2, ad2, m2, dn2, E);
  k_self_agg<1, 64><<<nb((long)N * 64), B, 0, stream>>>(H2, as2, ad2, m2, dn2, out, (long)N * 64);
  k_edge_agg<1, 64><<<nb((long)E * 64), B, 0, stream>>>(src, dst, H2, as2, ad2, m2, dn2, out, (long)E * 64);
  k_bias<64, false><<<nb((long)N * 64), B, 0, stream>>>(out, b2, (long)N * 64);
}

// Round 2
// 394.993 us; speedup vs baseline: 2.1295x; 2.1295x over previous
//
#include <hip/hip_runtime.h>

#define NEG 0.2f
#define EPSV 1e-16f
#define CAP1 128
#define CAP2 128

__device__ __forceinline__ float lrelu(float x) { return x > 0.f ? x : NEG * x; }

// ---------------- CSR build ----------------
__global__ void k_zero(int* __restrict__ p, int n) {
  int t = blockIdx.x * 256 + threadIdx.x;
  if (t < n) p[t] = 0;
}
__global__ void k_hist(const int* __restrict__ dst, int* __restrict__ cnt, int E) {
  int t = blockIdx.x * 256 + threadIdx.x;
  if (t < E) atomicAdd(&cnt[dst[t]], 1);
}
__global__ __launch_bounds__(1024) void k_scan(const int* __restrict__ cnt,
                                               int* __restrict__ row_ptr, int N) {
  __shared__ int sh[1024];
  int carry = 0;
  for (int base = 0; base < N; base += 1024) {
    int t = base + threadIdx.x;
    int v = (t < N) ? cnt[t] : 0;
    sh[threadIdx.x] = v;
    __syncthreads();
    for (int off = 1; off < 1024; off <<= 1) {
      int add = (threadIdx.x >= off) ? sh[threadIdx.x - off] : 0;
      __syncthreads();
      sh[threadIdx.x] += add;
      __syncthreads();
    }
    if (t < N) row_ptr[t] = carry + sh[threadIdx.x] - v;  // exclusive
    carry += sh[1023];
    __syncthreads();
  }
  if (threadIdx.x == 0) row_ptr[N] = carry;
}
__global__ void k_copy(const int* __restrict__ a, int* __restrict__ b, int n) {
  int t = blockIdx.x * 256 + threadIdx.x;
  if (t < n) b[t] = a[t];
}
__global__ void k_scatter(const int* __restrict__ src, const int* __restrict__ dst,
                          int* __restrict__ cursor, int* __restrict__ csr_src, int E) {
  int t = blockIdx.x * 256 + threadIdx.x;
  if (t >= E) return;
  int i = dst[t];
  int pos = atomicAdd(&cursor[i], 1);
  csr_src[pos] = src[t];
}

// ---------------- GEMM: Hout[N,M] = X[N,K] @ W[K,M] ----------------
template <int K, int M, int R>
__global__ __launch_bounds__(256) void k_gemm(const float* __restrict__ X,
                                              const float* __restrict__ W,
                                              float* __restrict__ Hout, int N) {
  __shared__ float ws[K * M];
  __shared__ float xs[R * K];
  const int tid = threadIdx.x;
  for (int idx = tid * 4; idx < K * M; idx += 1024)
    *(float4*)&ws[idx] = *(const float4*)&W[idx];
  const long row0 = (long)blockIdx.x * R;
  const int nrow = (int)min((long)R, (long)N - row0);
  for (int idx = tid * 4; idx < R * K; idx += 1024) {
    int r = idx / K;
    float4 v = make_float4(0.f, 0.f, 0.f, 0.f);
    if (r < nrow) v = *(const float4*)&X[row0 * K + idx];
    *(float4*)&xs[idx] = v;
  }
  __syncthreads();
  constexpr int NCT = M / 4;
  constexpr int RS = 256 / NCT;
  const int c0 = (tid % NCT) * 4;
  const int rslot = tid / NCT;
  for (int r = rslot; r < R; r += RS) {
    float4 acc = make_float4(0.f, 0.f, 0.f, 0.f);
#pragma unroll
    for (int k = 0; k < K; k += 4) {
      float4 xv = *(float4*)&xs[r * K + k];
      float4 w0 = *(float4*)&ws[(k + 0) * M + c0];
      float4 w1 = *(float4*)&ws[(k + 1) * M + c0];
      float4 w2 = *(float4*)&ws[(k + 2) * M + c0];
      float4 w3 = *(float4*)&ws[(k + 3) * M + c0];
      acc.x += xv.x * w0.x + xv.y * w1.x + xv.z * w2.x + xv.w * w3.x;
      acc.y += xv.x * w0.y + xv.y * w1.y + xv.z * w2.y + xv.w * w3.y;
      acc.z += xv.x * w0.z + xv.y * w1.z + xv.z * w2.z + xv.w * w3.z;
      acc.w += xv.x * w0.w + xv.y * w1.w + xv.z * w2.w + xv.w * w3.w;
    }
    if (r < nrow) *(float4*)&Hout[(row0 + r) * M + c0] = acc;
  }
}

// ---------------- attention dots ----------------
template <int H, int C>
__global__ void k_att(const float* __restrict__ Hf, const float* __restrict__ atts,
                      const float* __restrict__ attd, float* __restrict__ as_,
                      float* __restrict__ ad_, int N) {
  int t = blockIdx.x * 256 + threadIdx.x;
  if (t >= N * H) return;
  int n = t / H, h = t % H;
  const float* hp = Hf + (long)n * (H * C) + h * C;
  const float* sp = atts + h * C;
  const float* dp = attd + h * C;
  float s = 0.f, d = 0.f;
#pragma unroll
  for (int c = 0; c < C; c += 4) {
    float4 hv = *(const float4*)&hp[c];
    float4 sv = *(const float4*)&sp[c];
    float4 dv = *(const float4*)&dp[c];
    s += hv.x * sv.x + hv.y * sv.y + hv.z * sv.z + hv.w * sv.w;
    d += hv.x * dv.x + hv.y * dv.y + hv.z * dv.z + hv.w * dv.w;
  }
  as_[t] = s;
  ad_[t] = d;
}

// ---------------- fused per-node softmax+aggregate, layer 1 (H=8,C=16) ----------------
__global__ __launch_bounds__(256) void k_node1(const int* __restrict__ row_ptr,
                                               const int* __restrict__ csr_src,
                                               const float* __restrict__ Hf,
                                               const float* __restrict__ as_,
                                               const float* __restrict__ ad_,
                                               const float* __restrict__ bias,
                                               float* __restrict__ out, int N) {
  __shared__ float pl[4][CAP1 * 8];
  __shared__ int jl[4][CAP1];
  __shared__ float sm_m[4][8], sm_r[4][8], sm_p[4][8];
  const int wid = threadIdx.x >> 6, lane = threadIdx.x & 63;
  const int i = blockIdx.x * 4 + wid;
  const bool active = i < N;
  const int ii = active ? i : (N - 1);
  const int beg = row_ptr[ii];
  const int deg = active ? (row_ptr[ii + 1] - beg) : 0;

  float4 d0 = *(const float4*)&ad_[ii * 8], d1 = *(const float4*)&ad_[ii * 8 + 4];
  float4 s0 = *(const float4*)&as_[ii * 8], s1 = *(const float4*)&as_[ii * 8 + 4];
  float adv[8] = {d0.x, d0.y, d0.z, d0.w, d1.x, d1.y, d1.z, d1.w};
  float asv[8] = {s0.x, s0.y, s0.z, s0.w, s1.x, s1.y, s1.z, s1.w};
  float aself[8], m[8];
#pragma unroll
  for (int h = 0; h < 8; h++) {
    aself[h] = lrelu(asv[h] + adv[h]);
    m[h] = aself[h];
  }
  // phase A: alphas -> LDS, running max
  for (int e = lane; e < deg; e += 64) {
    int j = csr_src[beg + e];
    float4 a0 = *(const float4*)&as_[j * 8], a1 = *(const float4*)&as_[j * 8 + 4];
    float av[8] = {a0.x, a0.y, a0.z, a0.w, a1.x, a1.y, a1.z, a1.w};
#pragma unroll
    for (int h = 0; h < 8; h++) {
      float a = lrelu(av[h] + adv[h]);
      if (e < CAP1) pl[wid][e * 8 + h] = a;
      m[h] = fmaxf(m[h], a);
    }
    if (e < CAP1) jl[wid][e] = j;
  }
#pragma unroll
  for (int h = 0; h < 8; h++)
#pragma unroll
    for (int off = 32; off > 0; off >>= 1) m[h] = fmaxf(m[h], __shfl_xor(m[h], off));
  // phase B: exp + sum (lane-private LDS slots)
  float ss[8] = {0.f, 0.f, 0.f, 0.f, 0.f, 0.f, 0.f, 0.f};
  for (int e = lane; e < deg; e += 64) {
    if (e < CAP1) {
#pragma unroll
      for (int h = 0; h < 8; h++) {
        float p = __expf(pl[wid][e * 8 + h] - m[h]);
        pl[wid][e * 8 + h] = p;
        ss[h] += p;
      }
    } else {  // overflow path (effectively never taken)
      int j = csr_src[beg + e];
      float4 a0 = *(const float4*)&as_[j * 8], a1 = *(const float4*)&as_[j * 8 + 4];
      float av[8] = {a0.x, a0.y, a0.z, a0.w, a1.x, a1.y, a1.z, a1.w};
#pragma unroll
      for (int h = 0; h < 8; h++) ss[h] += __expf(lrelu(av[h] + adv[h]) - m[h]);
    }
  }
#pragma unroll
  for (int h = 0; h < 8; h++)
#pragma unroll
    for (int off = 32; off > 0; off >>= 1) ss[h] += __shfl_xor(ss[h], off);
#pragma unroll
  for (int h = 0; h < 8; h++) {
    float pself = __expf(aself[h] - m[h]);
    float rd = 1.f / (ss[h] + pself + EPSV);
    if (lane == h) {
      sm_m[wid][h] = m[h];
      sm_r[wid][h] = rd;
      sm_p[wid][h] = pself;
    }
  }
  __syncthreads();
  // phase C: aggregate; lane owns channels f0,f0+1
  const int f0 = lane * 2, hf = lane >> 3;
  const float rdh = sm_r[wid][hf], psh = sm_p[wid][hf], mh = sm_m[wid][hf];
  float2 hv = *(const float2*)&Hf[(long)ii * 128 + f0];
  float accx = psh * hv.x, accy = psh * hv.y;
  for (int e = 0; e < deg; e++) {
    int j;
    float p;
    if (e < CAP1) {
      j = jl[wid][e];
      p = pl[wid][e * 8 + hf];
    } else {
      j = csr_src[beg + e];
      p = __expf(lrelu(as_[j * 8 + hf] + adv[hf]) - mh);
    }
    float2 v = *(const float2*)&Hf[(long)j * 128 + f0];
    accx += p * v.x;
    accy += p * v.y;
  }
  float2 b = *(const float2*)&bias[f0];
  float2 o;
  o.x = fmaxf(accx * rdh + b.x, 0.f);
  o.y = fmaxf(accy * rdh + b.y, 0.f);
  if (active) *(float2*)&out[(long)i * 128 + f0] = o;
}

// ---------------- fused per-node softmax+aggregate, layer 2 (H=1,C=64) ----------------
__global__ __launch_bounds__(256) void k_node2(const int* __restrict__ row_ptr,
                                               const int* __restrict__ csr_src,
                                               const float* __restrict__ Hf,
                                               const float* __restrict__ as_,
                                               const float* __restrict__ ad_,
                                               const float* __restrict__ bias,
                                               float* __restrict__ out, int N) {
  __shared__ float pl[4][CAP2];
  __shared__ int jl[4][CAP2];
  const int wid = threadIdx.x >> 6, lane = threadIdx.x & 63;
  const int i = blockIdx.x * 4 + wid;
  const bool active = i < N;
  const int ii = active ? i : (N - 1);
  const int beg = row_ptr[ii];
  const int deg = active ? (row_ptr[ii + 1] - beg) : 0;

  const float adi = ad_[ii];
  const float aself = lrelu(as_[ii] + adi);
  float m = aself;
  for (int e = lane; e < deg; e += 64) {
    int j = csr_src[beg + e];
    float a = lrelu(as_[j] + adi);
    if (e < CAP2) {
      pl[wid][e] = a;
      jl[wid][e] = j;
    }
    m = fmaxf(m, a);
  }
#pragma unroll
  for (int off = 32; off > 0; off >>= 1) m = fmaxf(m, __shfl_xor(m, off));
  float ss = 0.f;
  for (int e = lane; e < deg; e += 64) {
    if (e < CAP2) {
      float p = __expf(pl[wid][e] - m);
      pl[wid][e] = p;
      ss += p;
    } else {
      int j = csr_src[beg + e];
      ss += __expf(lrelu(as_[j] + adi) - m);
    }
  }
#pragma unroll
  for (int off = 32; off > 0; off >>= 1) ss += __shfl_xor(ss, off);
  const float pself = __expf(aself - m);
  const float rd = 1.f / (ss + pself + EPSV);
  __syncthreads();
  float acc = pself * Hf[(long)ii * 64 + lane];
  for (int e = 0; e < deg; e++) {
    int j;
    float p;
    if (e < CAP2) {
      j = jl[wid][e];
      p = pl[wid][e];
    } else {
      j = csr_src[beg + e];
      p = __expf(lrelu(as_[j] + adi) - m);
    }
    acc += p * Hf[(long)j * 64 + lane];
  }
  if (active) out[(long)i * 64 + lane] = acc * rd + bias[lane];
}

extern "C" void kernel_launch(void* const* d_in, const int* in_sizes, int n_in,
                              void* d_out, int out_size, void* d_ws, size_t ws_size,
                              hipStream_t stream) {
  const float* x = (const float*)d_in[0];
  const int* ei = (const int*)d_in[1];
  const float* W1 = (const float*)d_in[2];
  const float* s1 = (const float*)d_in[3];
  const float* dd1 = (const float*)d_in[4];
  const float* b1 = (const float*)d_in[5];
  const float* W2 = (const float*)d_in[6];
  const float* s2 = (const float*)d_in[7];
  const float* dd2 = (const float*)d_in[8];
  const float* b2 = (const float*)d_in[9];
  const int N = in_sizes[0] / 128;
  const int E = in_sizes[1] / 2;
  const int* src = ei;      // row 0: source j
  const int* dst = ei + E;  // row 1: target i

  // workspace: H1[N*128] | as[N*8] | ad[N*8] | X2[N*128] | row_ptr[N+1] | csr_src[E]
  float* wsp = (float*)d_ws;
  float* H1 = wsp;
  float* as1 = H1 + (size_t)N * 128;
  float* ad1 = as1 + (size_t)N * 8;
  float* X2 = ad1 + (size_t)N * 8;
  int* row_ptr = (int*)(X2 + (size_t)N * 128);
  int* csr_src = row_ptr + (N + 1);
  int* cursor = (int*)as1;  // alias: dead before k_att writes as1
  float* out = (float*)d_out;
  float* H2 = H1;
  float* as2 = as1;
  float* ad2 = ad1;

  dim3 B(256);
  auto nb = [](long n) { return dim3((unsigned)((n + 255) / 256)); };

  // CSR build (by destination)
  k_zero<<<nb(N), B, 0, stream>>>(cursor, N);
  k_hist<<<nb(E), B, 0, stream>>>(dst, cursor, E);
  k_scan<<<dim3(1), dim3(1024), 0, stream>>>(cursor, row_ptr, N);
  k_copy<<<nb(N), B, 0, stream>>>(row_ptr, cursor, N);
  k_scatter<<<nb(E), B, 0, stream>>>(src, dst, cursor, csr_src, E);

  // Layer 1
  k_gemm<128, 128, 16><<<dim3((N + 15) / 16), B, 0, stream>>>(x, W1, H1, N);
  k_att<8, 16><<<nb((long)N * 8), B, 0, stream>>>(H1, s1, dd1, as1, ad1, N);
  k_node1<<<dim3((N + 3) / 4), B, 0, stream>>>(row_ptr, csr_src, H1, as1, ad1, b1, X2, N);

  // Layer 2
  k_gemm<128, 64, 16><<<dim3((N + 15) / 16), B, 0, stream>>>(X2, W2, H2, N);
  k_att<1, 64><<<nb(N), B, 0, stream>>>(H2, s2, dd2, as2, ad2, N);
  k_node2<<<dim3((N + 3) / 4), B, 0, stream>>>(row_ptr, csr_src, H2, as2, ad2, b2, out, N);
}

// Round 3
// 311.438 us; speedup vs baseline: 2.7008x; 1.2683x over previous
//
#include <hip/hip_runtime.h>

#define NEG 0.2f
#define EPSV 1e-16f
#define CAP1 128
#define CAP2 128

__device__ __forceinline__ float lrelu(float x) { return x > 0.f ? x : NEG * x; }

// ---------------- CSR build ----------------
__global__ void k_zero(int* __restrict__ p, int n) {
  int t = blockIdx.x * 256 + threadIdx.x;
  if (t < n) p[t] = 0;
}
__global__ void k_hist(const int* __restrict__ dst, int* __restrict__ cnt, int E) {
  int t = blockIdx.x * 256 + threadIdx.x;
  if (t < E) atomicAdd(&cnt[dst[t]], 1);
}
// phase 1: per-block exclusive scan into row_ptr, block sums to bsum
__global__ __launch_bounds__(1024) void k_scan1(const int* __restrict__ cnt,
                                                int* __restrict__ row_ptr,
                                                int* __restrict__ bsum, int N) {
  __shared__ int sh[1024];
  int t = blockIdx.x * 1024 + threadIdx.x;
  int v = (t < N) ? cnt[t] : 0;
  sh[threadIdx.x] = v;
  __syncthreads();
  for (int off = 1; off < 1024; off <<= 1) {
    int add = (threadIdx.x >= off) ? sh[threadIdx.x - off] : 0;
    __syncthreads();
    sh[threadIdx.x] += add;
    __syncthreads();
  }
  if (t < N) row_ptr[t] = sh[threadIdx.x] - v;  // exclusive within block
  if (threadIdx.x == 1023) bsum[blockIdx.x] = sh[1023];
}
// phase 2: single-wave exclusive scan of block sums (nb <= 64), total -> row_ptr[N]
__global__ __launch_bounds__(64) void k_scan2(int* __restrict__ bsum,
                                              int* __restrict__ row_ptr, int nb, int N) {
  int tid = threadIdx.x;
  int v = (tid < nb) ? bsum[tid] : 0;
  int inc = v;
#pragma unroll
  for (int off = 1; off < 64; off <<= 1) {
    int u = __shfl_up(inc, off);
    if (tid >= off) inc += u;
  }
  if (tid < nb) bsum[tid] = inc - v;  // exclusive
  if (tid == 63) row_ptr[N] = inc;    // grand total
}
// phase 3: add block offsets in place; also produce cursor copy
__global__ void k_scan3(const int* __restrict__ bsum, int* __restrict__ row_ptr,
                        int* __restrict__ cursor, int N) {
  int t = blockIdx.x * 256 + threadIdx.x;
  if (t < N) {
    int v = row_ptr[t] + bsum[t >> 10];
    row_ptr[t] = v;
    cursor[t] = v;
  }
}
__global__ void k_scatter(const int* __restrict__ src, const int* __restrict__ dst,
                          int* __restrict__ cursor, int* __restrict__ csr_src, int E) {
  int t = blockIdx.x * 256 + threadIdx.x;
  if (t >= E) return;
  int i = dst[t];
  int pos = atomicAdd(&cursor[i], 1);
  csr_src[pos] = src[t];
}

// ---------------- GEMM: Hout[N,M] = X[N,K] @ W[K,M] ----------------
template <int K, int M, int R>
__global__ __launch_bounds__(256) void k_gemm(const float* __restrict__ X,
                                              const float* __restrict__ W,
                                              float* __restrict__ Hout, int N) {
  __shared__ float ws[K * M];
  __shared__ float xs[R * K];
  const int tid = threadIdx.x;
  for (int idx = tid * 4; idx < K * M; idx += 1024)
    *(float4*)&ws[idx] = *(const float4*)&W[idx];
  const long row0 = (long)blockIdx.x * R;
  const int nrow = (int)min((long)R, (long)N - row0);
  for (int idx = tid * 4; idx < R * K; idx += 1024) {
    int r = idx / K;
    float4 v = make_float4(0.f, 0.f, 0.f, 0.f);
    if (r < nrow) v = *(const float4*)&X[row0 * K + idx];
    *(float4*)&xs[idx] = v;
  }
  __syncthreads();
  constexpr int NCT = M / 4;
  constexpr int RS = 256 / NCT;
  const int c0 = (tid % NCT) * 4;
  const int rslot = tid / NCT;
  for (int r = rslot; r < R; r += RS) {
    float4 acc = make_float4(0.f, 0.f, 0.f, 0.f);
#pragma unroll
    for (int k = 0; k < K; k += 4) {
      float4 xv = *(float4*)&xs[r * K + k];
      float4 w0 = *(float4*)&ws[(k + 0) * M + c0];
      float4 w1 = *(float4*)&ws[(k + 1) * M + c0];
      float4 w2 = *(float4*)&ws[(k + 2) * M + c0];
      float4 w3 = *(float4*)&ws[(k + 3) * M + c0];
      acc.x += xv.x * w0.x + xv.y * w1.x + xv.z * w2.x + xv.w * w3.x;
      acc.y += xv.x * w0.y + xv.y * w1.y + xv.z * w2.y + xv.w * w3.y;
      acc.z += xv.x * w0.z + xv.y * w1.z + xv.z * w2.z + xv.w * w3.z;
      acc.w += xv.x * w0.w + xv.y * w1.w + xv.z * w2.w + xv.w * w3.w;
    }
    if (r < nrow) *(float4*)&Hout[(row0 + r) * M + c0] = acc;
  }
}

// ---------------- attention dots ----------------
template <int H, int C>
__global__ void k_att(const float* __restrict__ Hf, const float* __restrict__ atts,
                      const float* __restrict__ attd, float* __restrict__ as_,
                      float* __restrict__ ad_, int N) {
  int t = blockIdx.x * 256 + threadIdx.x;
  if (t >= N * H) return;
  int n = t / H, h = t % H;
  const float* hp = Hf + (long)n * (H * C) + h * C;
  const float* sp = atts + h * C;
  const float* dp = attd + h * C;
  float s = 0.f, d = 0.f;
#pragma unroll
  for (int c = 0; c < C; c += 4) {
    float4 hv = *(const float4*)&hp[c];
    float4 sv = *(const float4*)&sp[c];
    float4 dv = *(const float4*)&dp[c];
    s += hv.x * sv.x + hv.y * sv.y + hv.z * sv.z + hv.w * sv.w;
    d += hv.x * dv.x + hv.y * dv.y + hv.z * dv.z + hv.w * dv.w;
  }
  as_[t] = s;
  ad_[t] = d;
}

// ---------------- fused per-node softmax+aggregate, layer 1 (H=8,C=16) ----------------
__global__ __launch_bounds__(256) void k_node1(const int* __restrict__ row_ptr,
                                               const int* __restrict__ csr_src,
                                               const float* __restrict__ Hf,
                                               const float* __restrict__ as_,
                                               const float* __restrict__ ad_,
                                               const float* __restrict__ bias,
                                               float* __restrict__ out, int N) {
  __shared__ float pl[4][CAP1 * 8];
  __shared__ int jl[4][CAP1];
  __shared__ float sm_m[4][8], sm_r[4][8], sm_p[4][8];
  const int wid = threadIdx.x >> 6, lane = threadIdx.x & 63;
  const int i = blockIdx.x * 4 + wid;
  const bool active = i < N;
  const int ii = active ? i : (N - 1);
  const int beg = row_ptr[ii];
  const int deg = active ? (row_ptr[ii + 1] - beg) : 0;

  float4 d0 = *(const float4*)&ad_[ii * 8], d1 = *(const float4*)&ad_[ii * 8 + 4];
  float4 s0 = *(const float4*)&as_[ii * 8], s1 = *(const float4*)&as_[ii * 8 + 4];
  float adv[8] = {d0.x, d0.y, d0.z, d0.w, d1.x, d1.y, d1.z, d1.w};
  float asv[8] = {s0.x, s0.y, s0.z, s0.w, s1.x, s1.y, s1.z, s1.w};
  float aself[8], m[8];
#pragma unroll
  for (int h = 0; h < 8; h++) {
    aself[h] = lrelu(asv[h] + adv[h]);
    m[h] = aself[h];
  }
  for (int e = lane; e < deg; e += 64) {
    int j = csr_src[beg + e];
    float4 a0 = *(const float4*)&as_[j * 8], a1 = *(const float4*)&as_[j * 8 + 4];
    float av[8] = {a0.x, a0.y, a0.z, a0.w, a1.x, a1.y, a1.z, a1.w};
#pragma unroll
    for (int h = 0; h < 8; h++) {
      float a = lrelu(av[h] + adv[h]);
      if (e < CAP1) pl[wid][e * 8 + h] = a;
      m[h] = fmaxf(m[h], a);
    }
    if (e < CAP1) jl[wid][e] = j;
  }
#pragma unroll
  for (int h = 0; h < 8; h++)
#pragma unroll
    for (int off = 32; off > 0; off >>= 1) m[h] = fmaxf(m[h], __shfl_xor(m[h], off));
  float ss[8] = {0.f, 0.f, 0.f, 0.f, 0.f, 0.f, 0.f, 0.f};
  for (int e = lane; e < deg; e += 64) {
    if (e < CAP1) {
#pragma unroll
      for (int h = 0; h < 8; h++) {
        float p = __expf(pl[wid][e * 8 + h] - m[h]);
        pl[wid][e * 8 + h] = p;
        ss[h] += p;
      }
    } else {
      int j = csr_src[beg + e];
      float4 a0 = *(const float4*)&as_[j * 8], a1 = *(const float4*)&as_[j * 8 + 4];
      float av[8] = {a0.x, a0.y, a0.z, a0.w, a1.x, a1.y, a1.z, a1.w};
#pragma unroll
      for (int h = 0; h < 8; h++) ss[h] += __expf(lrelu(av[h] + adv[h]) - m[h]);
    }
  }
#pragma unroll
  for (int h = 0; h < 8; h++)
#pragma unroll
    for (int off = 32; off > 0; off >>= 1) ss[h] += __shfl_xor(ss[h], off);
#pragma unroll
  for (int h = 0; h < 8; h++) {
    float pself = __expf(aself[h] - m[h]);
    float rd = 1.f / (ss[h] + pself + EPSV);
    if (lane == h) {
      sm_m[wid][h] = m[h];
      sm_r[wid][h] = rd;
      sm_p[wid][h] = pself;
    }
  }
  __syncthreads();
  const int f0 = lane * 2, hf = lane >> 3;
  const float rdh = sm_r[wid][hf], psh = sm_p[wid][hf], mh = sm_m[wid][hf];
  float2 hv = *(const float2*)&Hf[(long)ii * 128 + f0];
  float accx = psh * hv.x, accy = psh * hv.y;
  for (int e = 0; e < deg; e++) {
    int j;
    float p;
    if (e < CAP1) {
      j = jl[wid][e];
      p = pl[wid][e * 8 + hf];
    } else {
      j = csr_src[beg + e];
      p = __expf(lrelu(as_[j * 8 + hf] + adv[hf]) - mh);
    }
    float2 v = *(const float2*)&Hf[(long)j * 128 + f0];
    accx += p * v.x;
    accy += p * v.y;
  }
  float2 b = *(const float2*)&bias[f0];
  float2 o;
  o.x = fmaxf(accx * rdh + b.x, 0.f);
  o.y = fmaxf(accy * rdh + b.y, 0.f);
  if (active) *(float2*)&out[(long)i * 128 + f0] = o;
}

// ---------------- fused per-node softmax+aggregate, layer 2 (H=1,C=64) ----------------
__global__ __launch_bounds__(256) void k_node2(const int* __restrict__ row_ptr,
                                               const int* __restrict__ csr_src,
                                               const float* __restrict__ Hf,
                                               const float* __restrict__ as_,
                                               const float* __restrict__ ad_,
                                               const float* __restrict__ bias,
                                               float* __restrict__ out, int N) {
  __shared__ float pl[4][CAP2];
  __shared__ int jl[4][CAP2];
  const int wid = threadIdx.x >> 6, lane = threadIdx.x & 63;
  const int i = blockIdx.x * 4 + wid;
  const bool active = i < N;
  const int ii = active ? i : (N - 1);
  const int beg = row_ptr[ii];
  const int deg = active ? (row_ptr[ii + 1] - beg) : 0;

  const float adi = ad_[ii];
  const float aself = lrelu(as_[ii] + adi);
  float m = aself;
  for (int e = lane; e < deg; e += 64) {
    int j = csr_src[beg + e];
    float a = lrelu(as_[j] + adi);
    if (e < CAP2) {
      pl[wid][e] = a;
      jl[wid][e] = j;
    }
    m = fmaxf(m, a);
  }
#pragma unroll
  for (int off = 32; off > 0; off >>= 1) m = fmaxf(m, __shfl_xor(m, off));
  float ss = 0.f;
  for (int e = lane; e < deg; e += 64) {
    if (e < CAP2) {
      float p = __expf(pl[wid][e] - m);
      pl[wid][e] = p;
      ss += p;
    } else {
      int j = csr_src[beg + e];
      ss += __expf(lrelu(as_[j] + adi) - m);
    }
  }
#pragma unroll
  for (int off = 32; off > 0; off >>= 1) ss += __shfl_xor(ss, off);
  const float pself = __expf(aself - m);
  const float rd = 1.f / (ss + pself + EPSV);
  __syncthreads();
  float acc = pself * Hf[(long)ii * 64 + lane];
  for (int e = 0; e < deg; e++) {
    int j;
    float p;
    if (e < CAP2) {
      j = jl[wid][e];
      p = pl[wid][e];
    } else {
      j = csr_src[beg + e];
      p = __expf(lrelu(as_[j] + adi) - m);
    }
    acc += p * Hf[(long)j * 64 + lane];
  }
  if (active) out[(long)i * 64 + lane] = acc * rd + bias[lane];
}

extern "C" void kernel_launch(void* const* d_in, const int* in_sizes, int n_in,
                              void* d_out, int out_size, void* d_ws, size_t ws_size,
                              hipStream_t stream) {
  const float* x = (const float*)d_in[0];
  const int* ei = (const int*)d_in[1];
  const float* W1 = (const float*)d_in[2];
  const float* s1 = (const float*)d_in[3];
  const float* dd1 = (const float*)d_in[4];
  const float* b1 = (const float*)d_in[5];
  const float* W2 = (const float*)d_in[6];
  const float* s2 = (const float*)d_in[7];
  const float* dd2 = (const float*)d_in[8];
  const float* b2 = (const float*)d_in[9];
  const int N = in_sizes[0] / 128;
  const int E = in_sizes[1] / 2;
  const int* src = ei;      // row 0: source j
  const int* dst = ei + E;  // row 1: target i

  // workspace: H1[N*128] | as[N*8] | ad[N*8] | X2[N*128] | row_ptr[N+1] | csr_src[E] | bsum[64]
  float* wsp = (float*)d_ws;
  float* H1 = wsp;
  float* as1 = H1 + (size_t)N * 128;
  float* ad1 = as1 + (size_t)N * 8;
  float* X2 = ad1 + (size_t)N * 8;
  int* row_ptr = (int*)(X2 + (size_t)N * 128);
  int* csr_src = row_ptr + (N + 1);
  int* bsum = csr_src + E;
  int* cursor = (int*)as1;  // alias: dead before k_att writes as1
  float* out = (float*)d_out;
  float* H2 = H1;
  float* as2 = as1;
  float* ad2 = ad1;

  dim3 B(256);
  auto nb = [](long n) { return dim3((unsigned)((n + 255) / 256)); };
  const int nblk = (N + 1023) / 1024;  // <= 64

  // CSR build (by destination)
  k_zero<<<nb(N), B, 0, stream>>>(cursor, N);
  k_hist<<<nb(E), B, 0, stream>>>(dst, cursor, E);
  k_scan1<<<dim3(nblk), dim3(1024), 0, stream>>>(cursor, row_ptr, bsum, N);
  k_scan2<<<dim3(1), dim3(64), 0, stream>>>(bsum, row_ptr, nblk, N);
  k_scan3<<<nb(N), B, 0, stream>>>(bsum, row_ptr, cursor, N);
  k_scatter<<<nb(E), B, 0, stream>>>(src, dst, cursor, csr_src, E);

  // Layer 1
  k_gemm<128, 128, 16><<<dim3((N + 15) / 16), B, 0, stream>>>(x, W1, H1, N);
  k_att<8, 16><<<nb((long)N * 8), B, 0, stream>>>(H1, s1, dd1, as1, ad1, N);
  k_node1<<<dim3((N + 3) / 4), B, 0, stream>>>(row_ptr, csr_src, H1, as1, ad1, b1, X2, N);

  // Layer 2
  k_gemm<128, 64, 16><<<dim3((N + 15) / 16), B, 0, stream>>>(X2, W2, H2, N);
  k_att<1, 64><<<nb(N), B, 0, stream>>>(H2, s2, dd2, as2, ad2, N);
  k_node2<<<dim3((N + 3) / 4), B, 0, stream>>>(row_ptr, csr_src, H2, as2, ad2, b2, out, N);
}